// Round 2
// baseline (2397.861 us; speedup 1.0000x reference)
//
#include <hip/hip_runtime.h>
#include <stdint.h>

#define BATCH 32768
#define DIM   256
#define NFEAT 4096
#define KTOP  32
#define KSPL  512          // split-K storage width (2 bf16 planes x 256)
#define RSEL  40           // candidate rank refined exactly

typedef __attribute__((ext_vector_type(8))) short bf16x8;
typedef __attribute__((ext_vector_type(4))) float f32x4;

// ---- order-preserving float->uint mapping (ascending) ----
__device__ __forceinline__ uint32_t f2u(float f) {
    uint32_t b = __float_as_uint(f);
    return (b & 0x80000000u) ? ~b : (b | 0x80000000u);
}

// ---- bf16 RNE via bit trick (no hip_bf16 dependency) ----
__device__ __forceinline__ ushort f2bf_rne(float f) {
    uint32_t u = __float_as_uint(f);
    uint32_t lsb = (u >> 16) & 1u;
    u += 0x7fffu + lsb;
    return (ushort)(u >> 16);
}
__device__ __forceinline__ float bf2f(ushort s) {
    return __uint_as_float(((uint32_t)s) << 16);
}

// ---- async global->LDS, 16B per lane ----
__device__ __forceinline__ void gload_lds16(const void* gsrc, void* ldsdst) {
    __builtin_amdgcn_global_load_lds(
        (const __attribute__((address_space(1))) uint32_t*)(uintptr_t)gsrc,
        (__attribute__((address_space(3))) uint32_t*)(uint32_t)(uintptr_t)ldsdst,
        16, 0, 0);
}

// ---- kernel 1: split xc=(x-mean)/std-b_dec into 2 bf16 planes [B][512] ----
__global__ __launch_bounds__(256) void prep_a_split(const float* __restrict__ x,
                                                    const float* __restrict__ mean,
                                                    const float* __restrict__ stdv,
                                                    const float* __restrict__ bdec,
                                                    ushort* __restrict__ Asp) {
    int g = blockIdx.x * 256 + threadIdx.x;    // float4 index over B*D/4
    int b = g >> 6;                            // 64 float4 per row
    int q = g & 63;
    float4 xv = ((const float4*)x)[g];
    float4 mv = ((const float4*)mean)[q];
    float4 sv = ((const float4*)stdv)[q];
    float4 bv = ((const float4*)bdec)[q];
    float c[4];
    c[0] = (xv.x - mv.x) / sv.x - bv.x;
    c[1] = (xv.y - mv.y) / sv.y - bv.y;
    c[2] = (xv.z - mv.z) / sv.z - bv.z;
    c[3] = (xv.w - mv.w) / sv.w - bv.w;
    ushort h0[4], h1[4];
#pragma unroll
    for (int j = 0; j < 4; j++) {
        h0[j] = f2bf_rne(c[j]);
        h1[j] = f2bf_rne(c[j] - bf2f(h0[j]));
    }
    uint2 s0 = { (uint32_t)h0[0] | ((uint32_t)h0[1] << 16),
                 (uint32_t)h0[2] | ((uint32_t)h0[3] << 16) };
    uint2 s1 = { (uint32_t)h1[0] | ((uint32_t)h1[1] << 16),
                 (uint32_t)h1[2] | ((uint32_t)h1[3] << 16) };
    int d0 = q * 4;
    *(uint2*)&Asp[(size_t)b * KSPL + d0]       = s0;
    *(uint2*)&Asp[(size_t)b * KSPL + 256 + d0] = s1;
}

// ---- kernel 2: split W_enc into 2 bf16 planes [N][512] ----
__global__ __launch_bounds__(256) void prep_b_split(const float* __restrict__ w,
                                                    ushort* __restrict__ Bsp) {
    int g = blockIdx.x * 256 + threadIdx.x;    // float4 index over N*D/4
    int n = g >> 6;
    int q = g & 63;
    float4 wv = ((const float4*)w)[g];
    float c[4] = { wv.x, wv.y, wv.z, wv.w };
    ushort h0[4], h1[4];
#pragma unroll
    for (int j = 0; j < 4; j++) {
        h0[j] = f2bf_rne(c[j]);
        h1[j] = f2bf_rne(c[j] - bf2f(h0[j]));
    }
    uint2 s0 = { (uint32_t)h0[0] | ((uint32_t)h0[1] << 16),
                 (uint32_t)h0[2] | ((uint32_t)h0[3] << 16) };
    uint2 s1 = { (uint32_t)h1[0] | ((uint32_t)h1[1] << 16),
                 (uint32_t)h1[2] | ((uint32_t)h1[3] << 16) };
    int d0 = q * 4;
    *(uint2*)&Bsp[(size_t)n * KSPL + d0]       = s0;
    *(uint2*)&Bsp[(size_t)n * KSPL + 256 + d0] = s1;
}

// ---- kernel 3: W_decT[n][d] = W_dec[d][n] ----
__global__ __launch_bounds__(256) void transpose_wdec(const float* __restrict__ wd,
                                                      float* __restrict__ wdt) {
    __shared__ float t[32][33];
    int bx = blockIdx.x, by = blockIdx.y;
    int lx = threadIdx.x & 31, ly = threadIdx.x >> 5;
#pragma unroll
    for (int i = 0; i < 4; i++) {
        int d = by * 32 + ly + i * 8;
        t[ly + i * 8][lx] = wd[(size_t)d * NFEAT + bx * 32 + lx];
    }
    __syncthreads();
#pragma unroll
    for (int i = 0; i < 4; i++) {
        int n = bx * 32 + ly + i * 8;
        wdt[(size_t)n * DIM + by * 32 + lx] = t[lx][ly + i * 8];
    }
}

// ---- kernel 4: bf16-split MFMA GEMM: hpre = Asp x Bsp^T (3 plane-pairs) + b_enc ----
// 128x128 tile, BK=32, 4 waves 2x2, mfma_f32_16x16x32_bf16, global_load_lds w=16.
__global__ __launch_bounds__(256) void encode_gemm(const ushort* __restrict__ Asp,
                                                   const ushort* __restrict__ Bsp,
                                                   const float* __restrict__ be,
                                                   float* __restrict__ hpre) {
    __shared__ ushort smem[8192];              // As 8KB | Bs 8KB
    ushort* As = smem;
    ushort* Bs = smem + 4096;

    int bid = blockIdx.x;
    int wg  = (bid & 7) * 1024 + (bid >> 3);   // XCD swizzle (8192 % 8 == 0)
    int nt  = wg & 31, mt = wg >> 5;           // n fastest -> A-panel L2 reuse
    int row0 = mt * 128, col0 = nt * 128;

    int t = threadIdx.x;
    int lane = t & 63, w = t >> 6;
    int wr = w >> 1, wc = w & 1;

    // staging: thread t covers 16B: row srow (+0/64), k-bytes scol*2
    int srow = t >> 2;
    int scol = (t & 3) * 8;
    const ushort* ga0 = Asp + (size_t)(row0 + srow) * KSPL + scol;
    const ushort* ga1 = ga0 + (size_t)64 * KSPL;
    const ushort* gb0 = Bsp + (size_t)(col0 + srow) * KSPL + scol;
    const ushort* gb1 = gb0 + (size_t)64 * KSPL;
    char* lA = (char*)As + t * 16;
    char* lB = (char*)Bs + t * 16;

    // fragment read offsets (bytes): row*64 + kgrp*16
    int aoff = ((wr * 64 + (lane & 15)) * 32 + (lane >> 4) * 8) * 2;
    int boff = ((wc * 64 + (lane & 15)) * 32 + (lane >> 4) * 8) * 2;

    f32x4 acc[4][4] = {};

    for (int p = 0; p < 3; ++p) {
        int kA = (p >> 1) * 256;               // planes: (0,0),(0,1),(1,0)
        int kB = (p & 1) * 256;
        for (int ko = 0; ko < 256; ko += 32) {
            __syncthreads();                   // previous frag reads done
            gload_lds16(ga0 + kA + ko, lA);
            gload_lds16(ga1 + kA + ko, lA + 4096);
            gload_lds16(gb0 + kB + ko, lB);
            gload_lds16(gb1 + kB + ko, lB + 4096);
            __syncthreads();                   // vmcnt(0) drain -> tile ready
            bf16x8 af[4], bf[4];
#pragma unroll
            for (int m = 0; m < 4; m++) af[m] = *(const bf16x8*)((char*)As + aoff + m * 1024);
#pragma unroll
            for (int n = 0; n < 4; n++) bf[n] = *(const bf16x8*)((char*)Bs + boff + n * 1024);
#pragma unroll
            for (int m = 0; m < 4; m++)
#pragma unroll
                for (int n = 0; n < 4; n++)
                    acc[m][n] = __builtin_amdgcn_mfma_f32_16x16x32_bf16(af[m], bf[n], acc[m][n], 0, 0, 0);
        }
    }

    // epilogue: C/D layout col=lane&15, row=(lane>>4)*4+reg
    int crow = row0 + wr * 64 + (lane >> 4) * 4;
    int ccol = col0 + wc * 64 + (lane & 15);
#pragma unroll
    for (int n = 0; n < 4; n++) {
        float bev = be[ccol + n * 16];
#pragma unroll
        for (int m = 0; m < 4; m++) {
            float* op = hpre + (size_t)(crow + m * 16) * NFEAT + ccol + n * 16;
#pragma unroll
            for (int r = 0; r < 4; r++)
                op[(size_t)r * NFEAT] = acc[m][n][r] + bev;
        }
    }
}

// ---- kernel 5: wave-per-row top-K with exact f32 refinement + hsp write + decode ----
__global__ __launch_bounds__(256) void topk_decode(const float* __restrict__ hpre,
                                                   const float* __restrict__ x,
                                                   const float* __restrict__ mean,
                                                   const float* __restrict__ stdv,
                                                   const float* __restrict__ bdec,
                                                   const float* __restrict__ Wenc,
                                                   const float* __restrict__ benc,
                                                   const float* __restrict__ wdt,
                                                   float* __restrict__ hsp,
                                                   float* __restrict__ xhat) {
    __shared__ float xcb[4][256];
    __shared__ int   candn[4][64];
    __shared__ float selv[4][32];
    __shared__ int   seln[4][32];

    int wv = threadIdx.x >> 6, lane = threadIdx.x & 63;
    int row = blockIdx.x * 4 + wv;

    // phase 0: exact f32 xc row into LDS (one float4 per lane)
    {
        float4 xv = ((const float4*)(x + (size_t)row * DIM))[lane];
        float4 mv = ((const float4*)mean)[lane];
        float4 sv = ((const float4*)stdv)[lane];
        float4 bv = ((const float4*)bdec)[lane];
        float4 o;
        o.x = (xv.x - mv.x) / sv.x - bv.x;
        o.y = (xv.y - mv.y) / sv.y - bv.y;
        o.z = (xv.z - mv.z) / sv.z - bv.z;
        o.w = (xv.w - mv.w) / sv.w - bv.w;
        ((float4*)xcb[wv])[lane] = o;
    }

    // phase 1: load 64 keys/lane (chunk c: n = c*256 + lane*4 + j)
    uint32_t u[64];
    const float4* hr = (const float4*)(hpre + (size_t)row * NFEAT);
#pragma unroll
    for (int c = 0; c < 16; c++) {
        float4 v = hr[c * 64 + lane];
        u[c * 4 + 0] = f2u(v.x);
        u[c * 4 + 1] = f2u(v.y);
        u[c * 4 + 2] = f2u(v.z);
        u[c * 4 + 3] = f2u(v.w);
    }

    // phase 2: bisect for RSEL-th largest key (exact on approx values)
    uint32_t lo = 0, hi = 0xFFFFFFFFu;
    for (int it = 0; it < 32; ++it) {
        uint32_t d = hi - lo;
        uint32_t mid = lo + (d >> 1) + (d & 1);   // upper mid, no overflow
        int c = 0;
#pragma unroll
        for (int i = 0; i < 64; i++) c += (u[i] >= mid) ? 1 : 0;
#pragma unroll
        for (int off = 32; off; off >>= 1) c += __shfl_xor(c, off);
        if (c >= RSEL) lo = mid; else hi = mid - 1;
    }
    uint32_t ustar = lo;

    // phase 3: compact candidate indices (>= ustar) to LDS
    int base = 0;
#pragma unroll
    for (int c = 0; c < 16; c++) {
#pragma unroll
        for (int j = 0; j < 4; j++) {
            bool pred = (u[c * 4 + j] >= ustar);
            unsigned long long mask = __ballot(pred);
            if (pred) {
                int pos = base + __popcll(mask & ((1ull << lane) - 1ull));
                if (pos < 64) candn[wv][pos] = c * 256 + lane * 4 + j;
            }
            base += __popcll(mask);
        }
    }
    int ccnt = base < 64 ? base : 64;             // >= RSEL by construction

    // phase 4: refine candidates with exact f32 dot (lane c -> candidate c)
    float rv = -3.4e38f;
    int   rn = 0x7FFFFFFF;
    {
        int n = (lane < ccnt) ? candn[wv][lane] : 0;
        const float4* wr_ = (const float4*)(Wenc + (size_t)n * DIM);
        const float4* xc4 = (const float4*)xcb[wv];
        float s = 0.f;
#pragma unroll 8
        for (int k = 0; k < 64; k++) {
            float4 a = xc4[k];                    // same addr all lanes: broadcast
            float4 b = wr_[k];
            s += a.x * b.x + a.y * b.y + a.z * b.z + a.w * b.w;
        }
        if (lane < ccnt) { rv = s + benc[n]; rn = n; }
    }

    // phase 5: bitonic sort 64 lanes, desc by value, ties asc by index (jax order)
#pragma unroll
    for (int k = 2; k <= 64; k <<= 1) {
#pragma unroll
        for (int j = k >> 1; j >= 1; j >>= 1) {
            float ov = __shfl_xor(rv, j);
            int   on = __shfl_xor(rn, j);
            bool lower = (lane & j) == 0;
            bool desc  = (lane & k) == 0;
            bool mineBetter = (rv > ov) || (rv == ov && rn < on);
            if ((lower == desc) != mineBetter) { rv = ov; rn = on; }
        }
    }
    if (lane < KTOP) { selv[wv][lane] = rv; seln[wv][lane] = rn; }

    // phase 6: dense h_sparse write (selected get refined values, else 0)
    float* ho = hsp + (size_t)row * NFEAT;
#pragma unroll
    for (int c = 0; c < 16; c++) {
        float4 w4 = { 0.f, 0.f, 0.f, 0.f };
#pragma unroll
        for (int j = 0; j < 4; j++) {
            if (u[c * 4 + j] >= ustar) {          // rare (~40/4096)
                int n = c * 256 + lane * 4 + j;
                float val = 0.f;
                for (int s = 0; s < KTOP; s++)
                    if (seln[wv][s] == n) val = selv[wv][s];
                ((float*)&w4)[j] = val;
            }
        }
        ((float4*)ho)[c * 64 + lane] = w4;
    }

    // phase 7: sparse decode (lane owns 4 dims)
    float4 acc = ((const float4*)bdec)[lane];
#pragma unroll 4
    for (int s = 0; s < KTOP; s++) {
        float v = selv[wv][s];
        int   n = seln[wv][s];
        float4 w4 = ((const float4*)(wdt + (size_t)n * DIM))[lane];
        acc.x += v * w4.x; acc.y += v * w4.y; acc.z += v * w4.z; acc.w += v * w4.w;
    }
    ((float4*)(xhat + (size_t)row * DIM))[lane] = acc;
}

extern "C" void kernel_launch(void* const* d_in, const int* in_sizes, int n_in,
                              void* d_out, int out_size, void* d_ws, size_t ws_size,
                              hipStream_t stream) {
    const float* x     = (const float*)d_in[0];
    const float* W_enc = (const float*)d_in[1];
    const float* b_enc = (const float*)d_in[2];
    const float* W_dec = (const float*)d_in[3];
    const float* b_dec = (const float*)d_in[4];
    const float* mean  = (const float*)d_in[5];
    const float* stdv  = (const float*)d_in[6];

    float* out  = (float*)d_out;
    float* xhat = out;                                   // (B, D)
    float* hsp  = out + (size_t)BATCH * DIM;             // (B, N)
    float* hpre = hsp + (size_t)BATCH * NFEAT;           // (B, N)

    ushort* Asp = (ushort*)d_ws;                         // B*512 bf16   (33.6 MB)
    ushort* Bsp = Asp + (size_t)BATCH * KSPL;            // N*512 bf16   ( 4.2 MB)
    float*  wdt = (float*)(Bsp + (size_t)NFEAT * KSPL);  // N*D f32      ( 4.2 MB)

    prep_a_split<<<(BATCH * DIM / 4) / 256, 256, 0, stream>>>(x, mean, stdv, b_dec, Asp);
    prep_b_split<<<(NFEAT * DIM / 4) / 256, 256, 0, stream>>>(W_enc, Bsp);
    transpose_wdec<<<dim3(NFEAT / 32, DIM / 32), 256, 0, stream>>>(W_dec, wdt);
    encode_gemm<<<(BATCH / 128) * (NFEAT / 128), 256, 0, stream>>>(Asp, Bsp, b_enc, hpre);
    topk_decode<<<BATCH / 4, 256, 0, stream>>>(hpre, x, mean, stdv, b_dec,
                                               W_enc, b_enc, wdt, hsp, xhat);
}